// Round 1
// 235.322 us; speedup vs baseline: 1.0203x; 1.0203x over previous
//
#include <hip/hip_runtime.h>
#include <math.h>

#define N_TOT   196608      // B*HW*SPP = 4*16384*3
#define HWSPP   49152       // 16384*3
#define RGF     82          // floats per raw gaussian (linear LDS stride now)
#define NGB     3072        // gauss blocks
#define NFB     1024        // feat blocks

#define OFF_MEANS 0
#define OFF_COV   589824
#define OFF_SH    2359296
#define OFF_OP    17104896
#define OFF_FEAT  17301504
#define OFF_SCL   29884416
#define OFF_ROT   30474240

// workspace float layout: [0,660) D matrices (b*165 + loff[l]); [660,696) Kinv b*9; [696,700) multiplier
__device__ __constant__ int c_loff[5] = {0, 1, 10, 35, 84};

__device__ __forceinline__ float sigmoidf_(float x) { return 1.0f / (1.0f + expf(-x)); }

typedef __attribute__((address_space(3))) void lds_void;
typedef __attribute__((address_space(1))) void gmem_void;

// ---------------- setup: angles + Wigner D. One wave per (b,l). (unchanged) ----------------
__global__ __launch_bounds__(64) void setup_kernel(
    const float* __restrict__ extr, const float* __restrict__ intr,
    const int* __restrict__ img_h, const int* __restrict__ img_w,
    float* __restrict__ ws)
{
  const int b = blockIdx.x / 5;
  const int l = blockIdx.x % 5;
  const int n = 2 * l + 1;
  const int nn = n * n;
  const int t = threadIdx.x;

  __shared__ double Qr[81], Qi[81], X0c[81];
  __shared__ double X0r[81], U[9];
  __shared__ double A_[81], P0[81], P1[81], E0[81], E1[81];

  const float* Ex = extr + b * 16;
  double R00 = Ex[0], R01 = Ex[1], R02 = Ex[2];
  double R11 = Ex[5];
  double R20 = Ex[8], R21 = Ex[9], R22 = Ex[10];
  double x0 = R01, x1 = R11, x2 = R21;
  double nr = sqrt(x0 * x0 + x1 * x1 + x2 * x2);
  x0 /= nr; x1 /= nr; x2 /= nr;
  double beta  = acos(fmin(1.0, fmax(-1.0, x1)));
  double alpha = atan2(x0, x2);
  double ca_ = cos(alpha), sa_ = sin(alpha);
  double gamma = atan2(ca_ * R02 - sa_ * R22, ca_ * R00 - sa_ * R20);

  if (l == 0 && t == 0) {
    const float* K = intr + b * 9;
    double k00=K[0],k01=K[1],k02=K[2],k10=K[3],k11=K[4],k12=K[5],k20=K[6],k21=K[7],k22=K[8];
    double det = k00*(k11*k22-k12*k21) - k01*(k10*k22-k12*k20) + k02*(k10*k21-k11*k20);
    double id = 1.0 / det;
    float* kv = ws + 660 + b * 9;
    kv[0] = (float)((k11*k22-k12*k21)*id);
    kv[1] = (float)((k02*k21-k01*k22)*id);
    kv[2] = (float)((k01*k12-k02*k11)*id);
    kv[3] = (float)((k12*k20-k10*k22)*id);
    kv[4] = (float)((k00*k22-k02*k20)*id);
    kv[5] = (float)((k02*k10-k00*k12)*id);
    kv[6] = (float)((k10*k21-k11*k20)*id);
    kv[7] = (float)((k01*k20-k00*k21)*id);
    kv[8] = (float)((k00*k11-k01*k10)*id);
    double d2 = k00 * k11 - k01 * k10;
    double ps0 = 1.0 / (double)img_w[0];
    double ps1 = 1.0 / (double)img_h[0];
    double sum = (k11 * ps0 - k01 * ps1 - k10 * ps0 + k00 * ps1) / d2;
    ws[696 + b] = (float)(0.1 * sum);
  }

  for (int e = t; e < 81; e += 64) { Qr[e] = 0.0; Qi[e] = 0.0; X0c[e] = 0.0; }
  __syncthreads();
  if (t == 0) {
    const double irt2 = 0.70710678118654752440;
    for (int m = -l; m < 0; ++m) {
      Qr[(l + m) * n + (l - m)] = irt2;
      Qi[(l + m) * n + (l + m)] = -irt2;
    }
    Qr[l * n + l] = 1.0;
    for (int m = 1; m <= l; ++m) {
      double sg = (m & 1) ? -1.0 : 1.0;
      Qr[(l + m) * n + (l + m)] = sg * irt2;
      Qi[(l + m) * n + (l - m)] = sg * irt2;
    }
    for (int i = 0; i < n - 1; ++i) {
      double mi = (double)(-l + i);
      double ci = sqrt((double)(l * (l + 1)) - mi * (mi + 1.0));
      X0c[i * n + (i + 1)] = 0.5 * ci;
      X0c[(i + 1) * n + i] = -0.5 * ci;
    }
  }
  __syncthreads();
  for (int e = t; e < nn; e += 64) {
    int i = e / n, j = e % n; double s = 0, s2 = 0;
    for (int k = 0; k < n; ++k) { s += X0c[i*n+k]*Qr[k*n+j]; s2 += X0c[i*n+k]*Qi[k*n+j]; }
    P0[e] = s; P1[e] = s2;
  }
  __syncthreads();
  for (int e = t; e < nn; e += 64) {
    int a = e / n, c = e % n; double s = 0;
    for (int r = 0; r < n; ++r) s += Qr[r*n+a]*P0[r*n+c] + Qi[r*n+a]*P1[r*n+c];
    X0r[e] = s;
  }
  if (t < n) {
    int i = t, j = 2 * l - i; double s1 = 0;
    for (int r = 0; r < n; ++r) {
      double mr = (double)(r - l);
      s1 += mr * (Qi[r*n+i]*Qr[r*n+j] - Qr[r*n+i]*Qi[r*n+j]);
    }
    U[i] = s1;
  }
  __syncthreads();

  const double ths = -beta / 64.0;
  for (int e = t; e < nn; e += 64) { A_[e] = ths * X0r[e]; P0[e] = A_[e]; }
  double Ereg[2];
  {
    int ii = 0;
    for (int e = t; e < nn; e += 64) { Ereg[ii++] = ((e/n)==(e%n) ? 1.0 : 0.0) + ths * X0r[e]; }
  }
  __syncthreads();
  double* Pc = P0; double* Pn = P1;
  for (int k = 2; k <= 12; ++k) {
    int ii = 0;
    for (int e = t; e < nn; e += 64) {
      int i = e / n, j = e % n; double s = 0;
      for (int kk = 0; kk < n; ++kk) s += Pc[i*n+kk] * A_[kk*n+j];
      s /= (double)k;
      Pn[e] = s; Ereg[ii++] += s;
    }
    __syncthreads();
    double* tmp = Pc; Pc = Pn; Pn = tmp;
  }
  {
    int ii = 0;
    for (int e = t; e < nn; e += 64) E0[e] = Ereg[ii++];
  }
  __syncthreads();
  double* Es = E0; double* Ed = E1;
  for (int q = 0; q < 6; ++q) {
    for (int e = t; e < nn; e += 64) {
      int i = e / n, j = e % n; double s = 0;
      for (int kk = 0; kk < n; ++kk) s += Es[i*n+kk] * Es[kk*n+j];
      Ed[e] = s;
    }
    __syncthreads();
    double* tmp = Es; Es = Ed; Ed = tmp;
  }

  for (int e = t; e < nn; e += 64) {
    int i = e / n, j = e % n;
    int i2 = 2 * l - i, j2 = 2 * l - j;
    double cai = cos(alpha * U[i]), sai = sin(alpha * U[i]);
    double cgj = cos(gamma * U[j]), sgj = sin(gamma * U[j]);
    double w1 = cgj * Es[i *n + j] - sgj * Es[i *n + j2];
    double w2 = cgj * Es[i2*n + j] - sgj * Es[i2*n + j2];
    ws[b * 165 + c_loff[l] + e] = (float)(cai * w1 + sai * w2);
  }
}

// ---------------- fused main kernel: 4096 blocks; idx%4==3 -> feat, else gauss ----------------
// LDS budget 6720 floats = 26.25 KB -> 6 blocks/CU.
// Gauss staging is now LINEAR stride-82 (enables global_load_lds width=16; accepts a 4-way
// bank alias on the fragment reads, which is cheaper than the old div/mod scatter).
// sIn region is reused as SH output staging (stride 75) after fragments are in registers.
__global__ __launch_bounds__(256, 6) void main_kernel(
    const float* __restrict__ extr,
    const float* __restrict__ coords,
    const float* __restrict__ depths,
    const float* __restrict__ opac,
    const float* __restrict__ rg,
    const float* __restrict__ gf,
    const float* __restrict__ ws,
    float* __restrict__ out)
{
  __shared__ __align__(16) float smem[6720];
  const int t = threadIdx.x;
  const int bq = blockIdx.x >> 2;
  const int br = blockIdx.x & 3;

  if (br == 3) {
    // ---- features transpose-broadcast (feat block index bq in [0,1024)) ----
    // tile layout [c][hw], stride 65. float4 global loads (4 instrs/thread vs 16 scalar);
    // LDS scatter writes land 2 lanes/bank (free); transpose-read tile[tx*65+hw] conflict-free.
    float* tile = smem;              // 64*65 = 4160 floats
    const int b = bq >> 8;
    const int hw0 = (bq & 255) << 6;
    const float4* src4 = (const float4*)(gf + (size_t)b * (64 * 16384) + hw0);
#pragma unroll
    for (int k = 0; k < 4; ++k) {
      int flat = t + 256 * k;        // 0..1023
      int c = flat >> 4;             // channel 0..63
      int j = flat & 15;             // float4 within 64-wide hw tile
      float4 v = src4[(size_t)c * 4096 + j];
      float* tp = &tile[c * 65 + 4 * j];
      tp[0] = v.x; tp[1] = v.y; tp[2] = v.z; tp[3] = v.w;
    }
    __syncthreads();
    const int tx = t & 63, ty = t >> 6;
    float* dst = out + OFF_FEAT + ((size_t)(b * 16384 + hw0)) * 192;
    const float* trow = &tile[tx * 65];
    for (int r = ty; r < 192; r += 4) {
      dst[(size_t)r * 64 + tx] = trow[r / 3];
    }
    return;
  }

  // ---- per-gaussian path (gauss block index gb in [0,3072)) ----
  const int gb = bq * 3 + br;
  float* sSmall = smem + 5248;     // 1280: means[0,192) cov[192,768) scl[768,960) rot[960,1216) op[1216,1280)
  float* sD     = smem + 6528;     // 165
  float* sKinv  = smem + 6693;     // 9
  float* sRc    = smem + 6702;     // 9
  float* sOrig  = smem + 6711;     // 3
  float* sMult  = smem + 6714;     // 1

  const int g0 = gb * 64;
  const int b  = g0 / HWSPP;

  // prefetch per-gaussian scalars early (overlap with staging)
  float dpt = 0.f, opc = 0.f;
  float2 cxy = make_float2(0.f, 0.f);
  if (t < 64) {
    const int gidx = g0 + t;
    dpt = depths[gidx];
    opc = opac[gidx];
    cxy = ((const float2*)coords)[gidx];
  }

  if (t < 165) sD[t] = ws[b * 165 + t];
  else if (t < 174) sKinv[t - 165] = ws[660 + b * 9 + (t - 165)];
  else if (t < 183) { int k = t - 174; sRc[k] = extr[b * 16 + (k / 3) * 4 + (k % 3)]; }
  else if (t < 186) sOrig[t - 183] = extr[b * 16 + (t - 183) * 4 + 3];
  else if (t == 186) sMult[0] = ws[696 + b];

  // ---- linear rg staging: 1312 float4 = 64*82 floats. 1280 via global_load_lds, 32 tail. ----
  {
    const char* gbase = (const char*)(rg + (size_t)g0 * RGF);
    const int wbyte = (t & 192) << 4;           // wave-uniform LDS base: wid*64*16
#pragma unroll
    for (int k = 0; k < 5; ++k) {
      __builtin_amdgcn_global_load_lds(
          (const gmem_void*)(gbase + ((size_t)(k * 256 + t) << 4)),
          (lds_void*)((char*)smem + (k * 4096 + wbyte)),
          16, 0, 0);
    }
    if (t < 32) ((float4*)smem)[1280 + t] = ((const float4*)gbase)[1280 + t];
  }
  __syncthreads();

  // ---- phase 2a: read LDS inputs into registers (stride 82, 4-way alias — cheap) ----
  float reg[25];
  int gg = 0, ch = 0;
  if (t < 64) {
    const float* q = &smem[t * RGF];
#pragma unroll
    for (int j = 0; j < 7; ++j) reg[j] = q[j];
  } else {
    const int task = t - 64;        // 0..191
    gg = task & 63;
    ch = task >> 6;                 // 0..2 (uniform per wave)
    const float* shin = &smem[gg * RGF + 7 + ch * 25];
#pragma unroll
    for (int j = 0; j < 25; ++j) reg[j] = shin[j];
  }
  __syncthreads();

  // ---- phase 2b: compute; SH outputs overwrite smem[0,4800) (stride 75) ----
  if (t < 64) {
    const float mlt = sMult[0];
    float sc0 = (0.5f + 14.5f * sigmoidf_(reg[0])) * dpt * mlt;
    float sc1 = (0.5f + 14.5f * sigmoidf_(reg[1])) * dpt * mlt;
    float sc2 = (0.5f + 14.5f * sigmoidf_(reg[2])) * dpt * mlt;
    float r0 = reg[3], r1 = reg[4], r2 = reg[5], r3 = reg[6];
    float nr = sqrtf(r0*r0 + r1*r1 + r2*r2 + r3*r3) + 1e-8f;
    float qr = r0/nr, qi = r1/nr, qj = r2/nr, qk = r3/nr;
    float s2 = 2.0f / (qr*qr + qi*qi + qj*qj + qk*qk);
    float R00 = 1.0f - s2*(qj*qj + qk*qk);
    float R01 = s2*(qi*qj - qk*qr);
    float R02 = s2*(qi*qk + qj*qr);
    float R10 = s2*(qi*qj + qk*qr);
    float R11 = 1.0f - s2*(qi*qi + qk*qk);
    float R12 = s2*(qj*qk - qi*qr);
    float R20 = s2*(qi*qk - qj*qr);
    float R21 = s2*(qj*qk + qi*qr);
    float R22 = 1.0f - s2*(qi*qi + qj*qj);
    float v0 = sc0*sc0, v1 = sc1*sc1, v2 = sc2*sc2;
    float C00 = R00*R00*v0 + R01*R01*v1 + R02*R02*v2;
    float C01 = R00*R10*v0 + R01*R11*v1 + R02*R12*v2;
    float C02 = R00*R20*v0 + R01*R21*v1 + R02*R22*v2;
    float C11 = R10*R10*v0 + R11*R11*v1 + R12*R12*v2;
    float C12 = R10*R20*v0 + R11*R21*v1 + R12*R22*v2;
    float C22 = R20*R20*v0 + R21*R21*v1 + R22*R22*v2;
    float dx = sKinv[0]*cxy.x + sKinv[1]*cxy.y + sKinv[2];
    float dy = sKinv[3]*cxy.x + sKinv[4]*cxy.y + sKinv[5];
    float dz = sKinv[6]*cxy.x + sKinv[7]*cxy.y + sKinv[8];
    float inr = 1.0f / sqrtf(dx*dx + dy*dy + dz*dz);
    dx *= inr; dy *= inr; dz *= inr;
    float wx = sRc[0]*dx + sRc[1]*dy + sRc[2]*dz;
    float wy = sRc[3]*dx + sRc[4]*dy + sRc[5]*dz;
    float wz = sRc[6]*dx + sRc[7]*dy + sRc[8]*dz;
    sSmall[t*3+0] = sOrig[0] + wx * dpt;
    sSmall[t*3+1] = sOrig[1] + wy * dpt;
    sSmall[t*3+2] = sOrig[2] + wz * dpt;
    float* cc = &sSmall[192 + t*9];
    cc[0]=C00; cc[1]=C01; cc[2]=C02; cc[3]=C01; cc[4]=C11; cc[5]=C12; cc[6]=C02; cc[7]=C12; cc[8]=C22;
    float* ss = &sSmall[768 + t*3]; ss[0]=sc0; ss[1]=sc1; ss[2]=sc2;
    float* rr = &sSmall[960 + t*4]; rr[0]=qr; rr[1]=qi; rr[2]=qj; rr[3]=qk;
    sSmall[1216 + t] = opc;
  } else {
    float* shout = &smem[gg * 75 + ch * 25];   // overwrite staging region, stride 75
    shout[0] = sD[0] * reg[0];
#pragma unroll
    for (int i = 0; i < 3; ++i) {
      float a = sD[1+i*3]*reg[1] + sD[1+i*3+1]*reg[2] + sD[1+i*3+2]*reg[3];
      shout[1 + i] = (float)(0.1 * 0.25) * a;
    }
#pragma unroll
    for (int i = 0; i < 5; ++i) {
      float a = 0.f;
#pragma unroll
      for (int j = 0; j < 5; ++j) a += sD[10 + i*5 + j] * reg[4 + j];
      shout[4 + i] = (float)(0.1 * 0.0625) * a;
    }
#pragma unroll
    for (int i = 0; i < 7; ++i) {
      float a = 0.f;
#pragma unroll
      for (int j = 0; j < 7; ++j) a += sD[35 + i*7 + j] * reg[9 + j];
      shout[9 + i] = (float)(0.1 * 0.015625) * a;
    }
#pragma unroll
    for (int i = 0; i < 9; ++i) {
      float a = 0.f;
#pragma unroll
      for (int j = 0; j < 9; ++j) a += sD[84 + i*9 + j] * reg[16 + j];
      shout[16 + i] = (float)(0.1 * 0.00390625) * a;
    }
  }
  __syncthreads();

  // ---- phase 3: fully-vectorized coalesced global writes ----
  {
    const float4* s4 = (const float4*)smem;    // SH staging (4800 floats = 1200 float4)
    float4* osh = (float4*)(out + OFF_SH + (size_t)g0 * 75);
    for (int idx = t; idx < 1200; idx += 256) osh[idx] = s4[idx];

    if (t < 144) {
      ((float4*)(out + OFF_COV + (size_t)g0 * 9))[t] = ((const float4*)(sSmall + 192))[t];
    } else if (t < 192) {
      int i = t - 144;                          // 0..47: means + scales (48 float4 each)
      ((float4*)(out + OFF_MEANS + (size_t)g0 * 3))[i] = ((const float4*)sSmall)[i];
      ((float4*)(out + OFF_SCL   + (size_t)g0 * 3))[i] = ((const float4*)(sSmall + 768))[i];
    } else {
      int i = t - 192;                          // 0..63: rotations (64 float4) + opacity (16)
      ((float4*)(out + OFF_ROT + (size_t)g0 * 4))[i] = ((const float4*)(sSmall + 960))[i];
      if (i < 16)
        ((float4*)(out + OFF_OP + (size_t)g0))[i] = ((const float4*)(sSmall + 1216))[i];
    }
  }
}

extern "C" void kernel_launch(void* const* d_in, const int* in_sizes, int n_in,
                              void* d_out, int out_size, void* d_ws, size_t ws_size,
                              hipStream_t stream)
{
  const float* extr   = (const float*)d_in[0];
  const float* intr   = (const float*)d_in[1];
  const float* coords = (const float*)d_in[2];
  const float* depths = (const float*)d_in[3];
  const float* opac   = (const float*)d_in[4];
  const float* rg     = (const float*)d_in[5];
  const float* gf     = (const float*)d_in[6];
  const int*   ih     = (const int*)d_in[7];
  const int*   iw     = (const int*)d_in[8];
  float* out = (float*)d_out;
  float* ws  = (float*)d_ws;

  hipLaunchKernelGGL(setup_kernel, dim3(20), dim3(64), 0, stream, extr, intr, ih, iw, ws);
  hipLaunchKernelGGL(main_kernel, dim3(NGB + NFB), dim3(256), 0, stream,
                     extr, coords, depths, opac, rg, gf, ws, out);
}

// Round 2
// 234.682 us; speedup vs baseline: 1.0230x; 1.0027x over previous
//
#include <hip/hip_runtime.h>
#include <math.h>

#define N_TOT   196608      // B*HW*SPP = 4*16384*3
#define HWSPP   49152       // 16384*3
#define RGF     82          // floats per raw gaussian (linear LDS stride)
#define NGB     3072        // gauss blocks
#define NFB     1024        // feat blocks

#define OFF_MEANS 0
#define OFF_COV   589824
#define OFF_SH    2359296
#define OFF_OP    17104896
#define OFF_FEAT  17301504
#define OFF_SCL   29884416
#define OFF_ROT   30474240

// workspace float layout: [0,660) D matrices (b*165 + loff[l]); [660,696) Kinv b*9; [696,700) multiplier
__device__ __constant__ int c_loff[5] = {0, 1, 10, 35, 84};

__device__ __forceinline__ float sigmoidf_(float x) { return 1.0f / (1.0f + expf(-x)); }

typedef __attribute__((address_space(3))) void lds_void;
typedef __attribute__((address_space(1))) void gmem_void;

// ---------------- setup: angles + Wigner D. One wave per (b,l). (unchanged) ----------------
__global__ __launch_bounds__(64) void setup_kernel(
    const float* __restrict__ extr, const float* __restrict__ intr,
    const int* __restrict__ img_h, const int* __restrict__ img_w,
    float* __restrict__ ws)
{
  const int b = blockIdx.x / 5;
  const int l = blockIdx.x % 5;
  const int n = 2 * l + 1;
  const int nn = n * n;
  const int t = threadIdx.x;

  __shared__ double Qr[81], Qi[81], X0c[81];
  __shared__ double X0r[81], U[9];
  __shared__ double A_[81], P0[81], P1[81], E0[81], E1[81];

  const float* Ex = extr + b * 16;
  double R00 = Ex[0], R01 = Ex[1], R02 = Ex[2];
  double R11 = Ex[5];
  double R20 = Ex[8], R21 = Ex[9], R22 = Ex[10];
  double x0 = R01, x1 = R11, x2 = R21;
  double nr = sqrt(x0 * x0 + x1 * x1 + x2 * x2);
  x0 /= nr; x1 /= nr; x2 /= nr;
  double beta  = acos(fmin(1.0, fmax(-1.0, x1)));
  double alpha = atan2(x0, x2);
  double ca_ = cos(alpha), sa_ = sin(alpha);
  double gamma = atan2(ca_ * R02 - sa_ * R22, ca_ * R00 - sa_ * R20);

  if (l == 0 && t == 0) {
    const float* K = intr + b * 9;
    double k00=K[0],k01=K[1],k02=K[2],k10=K[3],k11=K[4],k12=K[5],k20=K[6],k21=K[7],k22=K[8];
    double det = k00*(k11*k22-k12*k21) - k01*(k10*k22-k12*k20) + k02*(k10*k21-k11*k20);
    double id = 1.0 / det;
    float* kv = ws + 660 + b * 9;
    kv[0] = (float)((k11*k22-k12*k21)*id);
    kv[1] = (float)((k02*k21-k01*k22)*id);
    kv[2] = (float)((k01*k12-k02*k11)*id);
    kv[3] = (float)((k12*k20-k10*k22)*id);
    kv[4] = (float)((k00*k22-k02*k20)*id);
    kv[5] = (float)((k02*k10-k00*k12)*id);
    kv[6] = (float)((k10*k21-k11*k20)*id);
    kv[7] = (float)((k01*k20-k00*k21)*id);
    kv[8] = (float)((k00*k11-k01*k10)*id);
    double d2 = k00 * k11 - k01 * k10;
    double ps0 = 1.0 / (double)img_w[0];
    double ps1 = 1.0 / (double)img_h[0];
    double sum = (k11 * ps0 - k01 * ps1 - k10 * ps0 + k00 * ps1) / d2;
    ws[696 + b] = (float)(0.1 * sum);
  }

  for (int e = t; e < 81; e += 64) { Qr[e] = 0.0; Qi[e] = 0.0; X0c[e] = 0.0; }
  __syncthreads();
  if (t == 0) {
    const double irt2 = 0.70710678118654752440;
    for (int m = -l; m < 0; ++m) {
      Qr[(l + m) * n + (l - m)] = irt2;
      Qi[(l + m) * n + (l + m)] = -irt2;
    }
    Qr[l * n + l] = 1.0;
    for (int m = 1; m <= l; ++m) {
      double sg = (m & 1) ? -1.0 : 1.0;
      Qr[(l + m) * n + (l + m)] = sg * irt2;
      Qi[(l + m) * n + (l - m)] = sg * irt2;
    }
    for (int i = 0; i < n - 1; ++i) {
      double mi = (double)(-l + i);
      double ci = sqrt((double)(l * (l + 1)) - mi * (mi + 1.0));
      X0c[i * n + (i + 1)] = 0.5 * ci;
      X0c[(i + 1) * n + i] = -0.5 * ci;
    }
  }
  __syncthreads();
  for (int e = t; e < nn; e += 64) {
    int i = e / n, j = e % n; double s = 0, s2 = 0;
    for (int k = 0; k < n; ++k) { s += X0c[i*n+k]*Qr[k*n+j]; s2 += X0c[i*n+k]*Qi[k*n+j]; }
    P0[e] = s; P1[e] = s2;
  }
  __syncthreads();
  for (int e = t; e < nn; e += 64) {
    int a = e / n, c = e % n; double s = 0;
    for (int r = 0; r < n; ++r) s += Qr[r*n+a]*P0[r*n+c] + Qi[r*n+a]*P1[r*n+c];
    X0r[e] = s;
  }
  if (t < n) {
    int i = t, j = 2 * l - i; double s1 = 0;
    for (int r = 0; r < n; ++r) {
      double mr = (double)(r - l);
      s1 += mr * (Qi[r*n+i]*Qr[r*n+j] - Qr[r*n+i]*Qi[r*n+j]);
    }
    U[i] = s1;
  }
  __syncthreads();

  const double ths = -beta / 64.0;
  for (int e = t; e < nn; e += 64) { A_[e] = ths * X0r[e]; P0[e] = A_[e]; }
  double Ereg[2];
  {
    int ii = 0;
    for (int e = t; e < nn; e += 64) { Ereg[ii++] = ((e/n)==(e%n) ? 1.0 : 0.0) + ths * X0r[e]; }
  }
  __syncthreads();
  double* Pc = P0; double* Pn = P1;
  for (int k = 2; k <= 12; ++k) {
    int ii = 0;
    for (int e = t; e < nn; e += 64) {
      int i = e / n, j = e % n; double s = 0;
      for (int kk = 0; kk < n; ++kk) s += Pc[i*n+kk] * A_[kk*n+j];
      s /= (double)k;
      Pn[e] = s; Ereg[ii++] += s;
    }
    __syncthreads();
    double* tmp = Pc; Pc = Pn; Pn = tmp;
  }
  {
    int ii = 0;
    for (int e = t; e < nn; e += 64) E0[e] = Ereg[ii++];
  }
  __syncthreads();
  double* Es = E0; double* Ed = E1;
  for (int q = 0; q < 6; ++q) {
    for (int e = t; e < nn; e += 64) {
      int i = e / n, j = e % n; double s = 0;
      for (int kk = 0; kk < n; ++kk) s += Es[i*n+kk] * Es[kk*n+j];
      Ed[e] = s;
    }
    __syncthreads();
    double* tmp = Es; Es = Ed; Ed = tmp;
  }

  for (int e = t; e < nn; e += 64) {
    int i = e / n, j = e % n;
    int i2 = 2 * l - i, j2 = 2 * l - j;
    double cai = cos(alpha * U[i]), sai = sin(alpha * U[i]);
    double cgj = cos(gamma * U[j]), sgj = sin(gamma * U[j]);
    double w1 = cgj * Es[i *n + j] - sgj * Es[i *n + j2];
    double w2 = cgj * Es[i2*n + j] - sgj * Es[i2*n + j2];
    ws[b * 165 + c_loff[l] + e] = (float)(cai * w1 + sai * w2);
  }
}

// ---------------- fused main kernel: 4096 blocks; idx%4==3 -> feat, else gauss ----------------
// LDS 6528 floats = 25.5 KB -> 6 blocks/CU. All wave-uniform constants (Wigner D, Kinv,
// Rc2w, origin, multiplier) are now read DIRECTLY from global with block-uniform addresses
// -> compiler emits merged s_load into SGPRs (scalar pipe), removing ~165 ds_read_b32 per
// SH thread from the LDS pipe. sIn region reused as SH output staging (stride 75).
__global__ __launch_bounds__(256, 6) void main_kernel(
    const float* __restrict__ extr,
    const float* __restrict__ coords,
    const float* __restrict__ depths,
    const float* __restrict__ opac,
    const float* __restrict__ rg,
    const float* __restrict__ gf,
    const float* __restrict__ ws,
    float* __restrict__ out)
{
  __shared__ __align__(16) float smem[6528];
  const int t = threadIdx.x;
  const int bq = blockIdx.x >> 2;
  const int br = blockIdx.x & 3;

  if (br == 3) {
    // ---- features transpose-broadcast (feat block index bq in [0,1024)) ----
    float* tile = smem;              // 64*65 = 4160 floats
    const int b = bq >> 8;
    const int hw0 = (bq & 255) << 6;
    const float4* src4 = (const float4*)(gf + (size_t)b * (64 * 16384) + hw0);
#pragma unroll
    for (int k = 0; k < 4; ++k) {
      int flat = t + 256 * k;        // 0..1023
      int c = flat >> 4;             // channel 0..63
      int j = flat & 15;             // float4 within 64-wide hw tile
      float4 v = src4[(size_t)c * 4096 + j];
      float* tp = &tile[c * 65 + 4 * j];
      tp[0] = v.x; tp[1] = v.y; tp[2] = v.z; tp[3] = v.w;
    }
    __syncthreads();
    const int tx = t & 63, ty = t >> 6;
    float* dst = out + OFF_FEAT + ((size_t)(b * 16384 + hw0)) * 192;
    const float* trow = &tile[tx * 65];
    for (int r = ty; r < 192; r += 4) {
      dst[(size_t)r * 64 + tx] = trow[r / 3];
    }
    return;
  }

  // ---- per-gaussian path (gauss block index gb in [0,3072)) ----
  const int gb = bq * 3 + br;
  float* sSmall = smem + 5248;     // 1280: means[0,192) cov[192,768) scl[768,960) rot[960,1216) op[1216,1280)

  const int g0 = gb * 64;
  const int b  = g0 / HWSPP;       // block-uniform

  // prefetch per-gaussian scalars early (overlap with staging)
  float dpt = 0.f, opc = 0.f;
  float2 cxy = make_float2(0.f, 0.f);
  if (t < 64) {
    const int gidx = g0 + t;
    dpt = depths[gidx];
    opc = opac[gidx];
    cxy = ((const float2*)coords)[gidx];
  }

  // ---- linear rg staging: 1312 float4 = 64*82 floats. 1280 via global_load_lds, 32 tail. ----
  {
    const char* gbase = (const char*)(rg + (size_t)g0 * RGF);
    const int wbyte = (t & 192) << 4;           // wave-uniform LDS base: wid*64*16
#pragma unroll
    for (int k = 0; k < 5; ++k) {
      __builtin_amdgcn_global_load_lds(
          (const gmem_void*)(gbase + ((size_t)(k * 256 + t) << 4)),
          (lds_void*)((char*)smem + (k * 4096 + wbyte)),
          16, 0, 0);
    }
    if (t < 32) ((float4*)smem)[1280 + t] = ((const float4*)gbase)[1280 + t];
  }
  __syncthreads();

  // ---- phase 2a: read LDS inputs into registers (stride 82, 4-way alias — cheap) ----
  float reg[25];
  int gg = 0, ch = 0;
  if (t < 64) {
    const float* q = &smem[t * RGF];
#pragma unroll
    for (int j = 0; j < 7; ++j) reg[j] = q[j];
  } else {
    const int task = t - 64;        // 0..191
    gg = task & 63;
    ch = task >> 6;                 // 0..2 (uniform per wave)
    const float* shin = &smem[gg * RGF + 7 + ch * 25];
#pragma unroll
    for (int j = 0; j < 25; ++j) reg[j] = shin[j];
  }
  __syncthreads();

  // ---- phase 2b: compute; SH outputs overwrite smem[0,4800) (stride 75) ----
  if (t < 64) {
    // all *uniform* constants read directly from global -> s_load into SGPRs
    const float* kv = ws + 660 + b * 9;
    const float mlt = ws[696 + b];
    const float* Ex = extr + b * 16;
    float sc0 = (0.5f + 14.5f * sigmoidf_(reg[0])) * dpt * mlt;
    float sc1 = (0.5f + 14.5f * sigmoidf_(reg[1])) * dpt * mlt;
    float sc2 = (0.5f + 14.5f * sigmoidf_(reg[2])) * dpt * mlt;
    float r0 = reg[3], r1 = reg[4], r2 = reg[5], r3 = reg[6];
    float nr = sqrtf(r0*r0 + r1*r1 + r2*r2 + r3*r3) + 1e-8f;
    float qr = r0/nr, qi = r1/nr, qj = r2/nr, qk = r3/nr;
    float s2 = 2.0f / (qr*qr + qi*qi + qj*qj + qk*qk);
    float R00 = 1.0f - s2*(qj*qj + qk*qk);
    float R01 = s2*(qi*qj - qk*qr);
    float R02 = s2*(qi*qk + qj*qr);
    float R10 = s2*(qi*qj + qk*qr);
    float R11 = 1.0f - s2*(qi*qi + qk*qk);
    float R12 = s2*(qj*qk - qi*qr);
    float R20 = s2*(qi*qk - qj*qr);
    float R21 = s2*(qj*qk + qi*qr);
    float R22 = 1.0f - s2*(qi*qi + qj*qj);
    float v0 = sc0*sc0, v1 = sc1*sc1, v2 = sc2*sc2;
    float C00 = R00*R00*v0 + R01*R01*v1 + R02*R02*v2;
    float C01 = R00*R10*v0 + R01*R11*v1 + R02*R12*v2;
    float C02 = R00*R20*v0 + R01*R21*v1 + R02*R22*v2;
    float C11 = R10*R10*v0 + R11*R11*v1 + R12*R12*v2;
    float C12 = R10*R20*v0 + R11*R21*v1 + R12*R22*v2;
    float C22 = R20*R20*v0 + R21*R21*v1 + R22*R22*v2;
    float dx = kv[0]*cxy.x + kv[1]*cxy.y + kv[2];
    float dy = kv[3]*cxy.x + kv[4]*cxy.y + kv[5];
    float dz = kv[6]*cxy.x + kv[7]*cxy.y + kv[8];
    float inr = 1.0f / sqrtf(dx*dx + dy*dy + dz*dz);
    dx *= inr; dy *= inr; dz *= inr;
    float wx = Ex[0]*dx + Ex[1]*dy + Ex[2]*dz;
    float wy = Ex[4]*dx + Ex[5]*dy + Ex[6]*dz;
    float wz = Ex[8]*dx + Ex[9]*dy + Ex[10]*dz;
    sSmall[t*3+0] = Ex[3]  + wx * dpt;
    sSmall[t*3+1] = Ex[7]  + wy * dpt;
    sSmall[t*3+2] = Ex[11] + wz * dpt;
    float* cc = &sSmall[192 + t*9];
    cc[0]=C00; cc[1]=C01; cc[2]=C02; cc[3]=C01; cc[4]=C11; cc[5]=C12; cc[6]=C02; cc[7]=C12; cc[8]=C22;
    float* ss = &sSmall[768 + t*3]; ss[0]=sc0; ss[1]=sc1; ss[2]=sc2;
    float* rr = &sSmall[960 + t*4]; rr[0]=qr; rr[1]=qi; rr[2]=qj; rr[3]=qk;
    sSmall[1216 + t] = opc;
  } else {
    // Wigner D read directly from global with uniform addresses -> merged s_loads (SGPRs),
    // zero LDS-pipe traffic for the matrix.
    const float* Db = ws + b * 165;
    float* shout = &smem[gg * 75 + ch * 25];   // overwrite staging region, stride 75
    shout[0] = Db[0] * reg[0];
#pragma unroll
    for (int i = 0; i < 3; ++i) {
      float a = Db[1+i*3]*reg[1] + Db[1+i*3+1]*reg[2] + Db[1+i*3+2]*reg[3];
      shout[1 + i] = (float)(0.1 * 0.25) * a;
    }
#pragma unroll
    for (int i = 0; i < 5; ++i) {
      float a = 0.f;
#pragma unroll
      for (int j = 0; j < 5; ++j) a += Db[10 + i*5 + j] * reg[4 + j];
      shout[4 + i] = (float)(0.1 * 0.0625) * a;
    }
#pragma unroll
    for (int i = 0; i < 7; ++i) {
      float a = 0.f;
#pragma unroll
      for (int j = 0; j < 7; ++j) a += Db[35 + i*7 + j] * reg[9 + j];
      shout[9 + i] = (float)(0.1 * 0.015625) * a;
    }
#pragma unroll
    for (int i = 0; i < 9; ++i) {
      float a = 0.f;
#pragma unroll
      for (int j = 0; j < 9; ++j) a += Db[84 + i*9 + j] * reg[16 + j];
      shout[16 + i] = (float)(0.1 * 0.00390625) * a;
    }
  }
  __syncthreads();

  // ---- phase 3: fully-vectorized coalesced global writes ----
  {
    const float4* s4 = (const float4*)smem;    // SH staging (4800 floats = 1200 float4)
    float4* osh = (float4*)(out + OFF_SH + (size_t)g0 * 75);
    for (int idx = t; idx < 1200; idx += 256) osh[idx] = s4[idx];

    if (t < 144) {
      ((float4*)(out + OFF_COV + (size_t)g0 * 9))[t] = ((const float4*)(sSmall + 192))[t];
    } else if (t < 192) {
      int i = t - 144;                          // 0..47: means + scales (48 float4 each)
      ((float4*)(out + OFF_MEANS + (size_t)g0 * 3))[i] = ((const float4*)sSmall)[i];
      ((float4*)(out + OFF_SCL   + (size_t)g0 * 3))[i] = ((const float4*)(sSmall + 768))[i];
    } else {
      int i = t - 192;                          // 0..63: rotations (64 float4) + opacity (16)
      ((float4*)(out + OFF_ROT + (size_t)g0 * 4))[i] = ((const float4*)(sSmall + 960))[i];
      if (i < 16)
        ((float4*)(out + OFF_OP + (size_t)g0))[i] = ((const float4*)(sSmall + 1216))[i];
    }
  }
}

extern "C" void kernel_launch(void* const* d_in, const int* in_sizes, int n_in,
                              void* d_out, int out_size, void* d_ws, size_t ws_size,
                              hipStream_t stream)
{
  const float* extr   = (const float*)d_in[0];
  const float* intr   = (const float*)d_in[1];
  const float* coords = (const float*)d_in[2];
  const float* depths = (const float*)d_in[3];
  const float* opac   = (const float*)d_in[4];
  const float* rg     = (const float*)d_in[5];
  const float* gf     = (const float*)d_in[6];
  const int*   ih     = (const int*)d_in[7];
  const int*   iw     = (const int*)d_in[8];
  float* out = (float*)d_out;
  float* ws  = (float*)d_ws;

  hipLaunchKernelGGL(setup_kernel, dim3(20), dim3(64), 0, stream, extr, intr, ih, iw, ws);
  hipLaunchKernelGGL(main_kernel, dim3(NGB + NFB), dim3(256), 0, stream,
                     extr, coords, depths, opac, rg, gf, ws, out);
}